// Round 15
// baseline (348353.125 us; speedup 1.0000x reference)
//
#include <hip/hip_runtime.h>
#include <hip/hip_bf16.h>

// Problem constants (fixed by setup_inputs)
#define B_    4
#define H_    32
#define W_    32
#define N_    1024      // H*W
#define CIN_  256
#define CHID_ 1024
#define C2_   512

// ---------------------------------------------------------------------------
// Naive fully-connected: out[m][o] = bias[o] + sum_k A[m][k] * W[o][k]
// ---------------------------------------------------------------------------
__global__ void fc_naive(const float* __restrict__ A, const float* __restrict__ Wt,
                         const float* __restrict__ bias, float* __restrict__ out,
                         int M, int O, int K)
{
    int gid = blockIdx.x * blockDim.x + threadIdx.x;
    if (gid >= M * O) return;
    int o = gid % O, m = gid / O;
    const float* ap = A + (size_t)m * K;
    const float* wp = Wt + (size_t)o * K;
    float acc = bias[o];
    for (int k = 0; k < K; ++k) acc += ap[k] * wp[k];
    out[(size_t)m * O + o] = acc;
}

// ---------------------------------------------------------------------------
// Naive conv2d (cross-correlation, literal translation of conv_general_dilated)
// Token-major activations: in[(b*N+n)*lda + c]; weights w[o][c][ky][kx] fp32.
// ---------------------------------------------------------------------------
template<int KS>
__global__ void conv_naive(const float* __restrict__ in, int lda,
                           const float* __restrict__ w, const float* __restrict__ bias,
                           float* __restrict__ out, int ldo, int Cout, int Cin)
{
    const int PAD = KS / 2, KK = KS * KS;
    int gid = blockIdx.x * blockDim.x + threadIdx.x;
    if (gid >= B_ * N_ * Cout) return;
    int o = gid % Cout;
    int n = (gid / Cout) % N_;
    int b = gid / (Cout * N_);
    int y = n >> 5, x = n & 31;
    float acc = bias[o];
    for (int ky = 0; ky < KS; ++ky) {
        int yy = y + ky - PAD;
        if (yy < 0 || yy >= H_) continue;
        for (int kx = 0; kx < KS; ++kx) {
            int xx = x + kx - PAD;
            if (xx < 0 || xx >= W_) continue;
            const float* ip = in + (size_t)(b * N_ + yy * W_ + xx) * lda;
            const float* wp = w + (size_t)o * Cin * KK + ky * KS + kx;
            for (int c = 0; c < Cin; ++c) acc += ip[c] * wp[(size_t)c * KK];
        }
    }
    out[(size_t)(b * N_ + n) * ldo + o] = acc;
}

// ---------------------------------------------------------------------------
// Bilinear sample for ONE tap j (literal translation)
// ---------------------------------------------------------------------------
template<int KS>
__global__ void bilinear_naive(const float* __restrict__ h, int lda,
                               const float* __restrict__ offb, int KK2,
                               float* __restrict__ samp, int j)
{
    const int PAD = KS / 2;
    int gid = blockIdx.x * blockDim.x + threadIdx.x;
    if (gid >= B_ * N_ * C2_) return;
    int c = gid % C2_;
    int n = (gid / C2_) % N_;
    int b = gid / (C2_ * N_);
    const float* op = offb + (size_t)(b * N_ + n) * KK2;
    float dy = op[2 * j], dx = op[2 * j + 1];
    int y = n >> 5, x = n & 31;
    float py = (float)(y - PAD + j / KS) + dy;
    float px = (float)(x - PAD + j % KS) + dx;
    float y0f = floorf(py), x0f = floorf(px);
    float fy = py - y0f, fx = px - x0f;
    int y0 = (int)y0f, x0 = (int)x0f;
    float wy[2] = {1.f - fy, fy};
    float wx[2] = {1.f - fx, fx};
    float acc = 0.f;
#pragma unroll
    for (int a = 0; a < 2; ++a) {
#pragma unroll
        for (int cc = 0; cc < 2; ++cc) {
            int yy = y0 + a, xx = x0 + cc;
            if (yy >= 0 && yy < H_ && xx >= 0 && xx < W_) {
                acc += wy[a] * wx[cc] * h[(size_t)(b * N_ + yy * W_ + xx) * lda + c];
            }
        }
    }
    samp[(size_t)(b * N_ + n) * C2_ + c] = acc;
}

// ---------------------------------------------------------------------------
// Per-tap accumulate: dacc[bn][o] (+)= sum_c samp[bn][c] * w[o][c][j]
// ---------------------------------------------------------------------------
__global__ void tap_gemm_naive(const float* __restrict__ samp, const float* __restrict__ w,
                               int KK, int j, float* __restrict__ dacc,
                               int Cout, int Cin, int init, const float* __restrict__ bias)
{
    int gid = blockIdx.x * blockDim.x + threadIdx.x;
    if (gid >= B_ * N_ * Cout) return;
    int o = gid % Cout;
    int bn = gid / Cout;
    const float* sp = samp + (size_t)bn * Cin;
    const float* wp = w + (size_t)o * Cin * KK + j;
    float acc = init ? bias[o] : dacc[(size_t)bn * Cout + o];
    for (int c = 0; c < Cin; ++c) acc += sp[c] * wp[(size_t)c * KK];
    dacc[(size_t)bn * Cout + o] = acc;
}

// ---------------------------------------------------------------------------
// LayerNorm (eps 1e-5) + exact GELU, fp32 in place
// ---------------------------------------------------------------------------
__global__ void ln_gelu_naive(float* __restrict__ ytok,
                              const float* __restrict__ g, const float* __restrict__ bt)
{
    int t = blockIdx.x * blockDim.x + threadIdx.x;
    if (t >= B_ * N_) return;
    float* row = ytok + (size_t)t * CHID_;
    float s = 0.f;
    for (int c = 0; c < CHID_; ++c) s += row[c];
    float mean = s / CHID_;
    float q = 0.f;
    for (int c = 0; c < CHID_; ++c) { float d = row[c] - mean; q += d * d; }
    float rstd = rsqrtf(q / CHID_ + 1e-5f);
    for (int c = 0; c < CHID_; ++c) {
        float v = (row[c] - mean) * rstd * g[c] + bt[c];
        row[c] = 0.5f * v * (1.f + erff(v * 0.70710678118654752f));
    }
}

// ---------------------------------------------------------------------------
// fc2 with FLOAT32 store (output buffer is fp32 — proven by R14 probe).
// ---------------------------------------------------------------------------
__global__ void fc2_naive(const float* __restrict__ A, const float* __restrict__ Wt,
                          const float* __restrict__ bias, float* __restrict__ out,
                          int M, int O, int K)
{
    int gid = blockIdx.x * blockDim.x + threadIdx.x;
    if (gid >= M * O) return;
    int o = gid % O, m = gid / O;
    const float* ap = A + (size_t)m * K;
    const float* wp = Wt + (size_t)o * K;
    float acc = bias[o];
    for (int k = 0; k < K; ++k) acc += ap[k] * wp[k];
    out[(size_t)m * O + o] = acc;
}

// ---------------------------------------------------------------------------
extern "C" void kernel_launch(void* const* d_in, const int* in_sizes, int n_in,
                              void* d_out, int out_size, void* d_ws, size_t ws_size,
                              hipStream_t stream) {
    const float* x       = (const float*)d_in[0];
    const float* fc1_w   = (const float*)d_in[3];
    const float* fc1_b   = (const float*)d_in[4];
    const float* off3_w  = (const float*)d_in[5];
    const float* off3_b  = (const float*)d_in[6];
    const float* conv3_w = (const float*)d_in[7];
    const float* conv3_b = (const float*)d_in[8];
    const float* off5_w  = (const float*)d_in[9];
    const float* off5_b  = (const float*)d_in[10];
    const float* conv5_w = (const float*)d_in[11];
    const float* conv5_b = (const float*)d_in[12];
    const float* ln_g    = (const float*)d_in[13];
    const float* ln_b    = (const float*)d_in[14];
    const float* fc2_w   = (const float*)d_in[15];
    const float* fc2_b   = (const float*)d_in[16];
    float* out = (float*)d_out;   // fp32 output (R14 probe: bf16 ruled out)

    char* ws = (char*)d_ws;
    float* h    = (float*)(ws + 0);           // 16 MiB
    float* ytok = (float*)(ws + 16777216);    // 16 MiB
    float* dacc = (float*)(ws + 33554432);    //  8 MiB
    float* samp = (float*)(ws + 41943040);    //  8 MiB
    float* offb = (float*)(ws + 50331648);    //  0.82 MiB (ws_size >= 51.2MB verified R5)

    const int TPB = 256;

    // fc1
    fc_naive<<<(B_*N_*CHID_ + TPB-1)/TPB, TPB, 0, stream>>>(x, fc1_w, fc1_b, h, B_*N_, CHID_, CIN_);

    // ---- branch 1 (k=3, pad=1), channels [0:512) of h ----
    conv_naive<3><<<(B_*N_*18 + TPB-1)/TPB, TPB, 0, stream>>>(h, CHID_, off3_w, off3_b, offb, 18, 18, C2_);
    for (int j = 0; j < 9; ++j) {
        bilinear_naive<3><<<(B_*N_*C2_ + TPB-1)/TPB, TPB, 0, stream>>>(h, CHID_, offb, 18, samp, j);
        tap_gemm_naive<<<(B_*N_*C2_ + TPB-1)/TPB, TPB, 0, stream>>>(samp, conv3_w, 9, j, dacc, C2_, C2_, j == 0, conv3_b);
    }
    conv_naive<3><<<(B_*N_*C2_ + TPB-1)/TPB, TPB, 0, stream>>>(dacc, C2_, conv3_w, conv3_b, ytok, CHID_, C2_, C2_);

    // ---- branch 2 (k=5, pad=2), channels [512:1024) of h ----
    conv_naive<5><<<(B_*N_*50 + TPB-1)/TPB, TPB, 0, stream>>>(h + C2_, CHID_, off5_w, off5_b, offb, 50, 50, C2_);
    for (int j = 0; j < 25; ++j) {
        bilinear_naive<5><<<(B_*N_*C2_ + TPB-1)/TPB, TPB, 0, stream>>>(h + C2_, CHID_, offb, 50, samp, j);
        tap_gemm_naive<<<(B_*N_*C2_ + TPB-1)/TPB, TPB, 0, stream>>>(samp, conv5_w, 25, j, dacc, C2_, C2_, j == 0, conv5_b);
    }
    conv_naive<5><<<(B_*N_*C2_ + TPB-1)/TPB, TPB, 0, stream>>>(dacc, C2_, conv5_w, conv5_b, ytok + C2_, CHID_, C2_, C2_);

    // LN + GELU
    ln_gelu_naive<<<(B_*N_ + TPB-1)/TPB, TPB, 0, stream>>>(ytok, ln_g, ln_b);

    // fc2 -> fp32 out
    fc2_naive<<<(B_*N_*CIN_ + TPB-1)/TPB, TPB, 0, stream>>>(ytok, fc2_w, fc2_b, out, B_*N_, CIN_, CHID_);
}